// Round 6
// baseline (217.670 us; speedup 1.0000x reference)
//
#include <hip/hip_runtime.h>
#include <hip/hip_bf16.h>

// ---------- types ----------
typedef short bf16x8 __attribute__((ext_vector_type(8)));
typedef float f32x4 __attribute__((ext_vector_type(4)));

typedef __attribute__((address_space(3))) unsigned int lds_u32;
typedef __attribute__((address_space(1))) const unsigned int gbl_cu32;

__device__ __forceinline__ void async_ld16(void* lds, const void* g) {
  __builtin_amdgcn_global_load_lds((gbl_cu32*)g, (lds_u32*)lds, 16, 0, 0);
}

__device__ __forceinline__ unsigned short f2bf(float f) {
  unsigned u = __builtin_bit_cast(unsigned, f);
  u += 0x7FFFu + ((u >> 16) & 1u);   // RNE; inputs finite
  return (unsigned short)(u >> 16);
}

// ---------- prep (merged): x->bf16, mask(qkv_w), mask(proj_w) ----------
__global__ void k_prep(const float* __restrict__ x, unsigned short* __restrict__ xo,
                       const float* __restrict__ w1, const float* __restrict__ m1,
                       unsigned short* __restrict__ o1,
                       const float* __restrict__ w2, const float* __restrict__ m2,
                       unsigned short* __restrict__ o2) {
  int blk = blockIdx.x;
  if (blk < 6144) {
    int i = blk * 256 + threadIdx.x;
    float4 v = ((const float4*)x)[i];
    ushort4 r;
    r.x = f2bf(v.x); r.y = f2bf(v.y); r.z = f2bf(v.z); r.w = f2bf(v.w);
    ((ushort4*)xo)[i] = r;
  } else if (blk < 6144 + 1728) {
    int i = (blk - 6144) * 256 + threadIdx.x;
    float4 wv = ((const float4*)w1)[i];
    float4 mv = ((const float4*)m1)[i];
    ushort4 r;
    r.x = f2bf(mv.x >= 0.005f ? wv.x : 0.0f);
    r.y = f2bf(mv.y >= 0.005f ? wv.y : 0.0f);
    r.z = f2bf(mv.z >= 0.005f ? wv.z : 0.0f);
    r.w = f2bf(mv.w >= 0.005f ? wv.w : 0.0f);
    ((ushort4*)o1)[i] = r;
  } else {
    int i = (blk - 6144 - 1728) * 256 + threadIdx.x;
    float4 wv = ((const float4*)w2)[i];
    float4 mv = ((const float4*)m2)[i];
    ushort4 r;
    r.x = f2bf(mv.x >= 0.005f ? wv.x : 0.0f);
    r.y = f2bf(mv.y >= 0.005f ? wv.y : 0.0f);
    r.z = f2bf(mv.z >= 0.005f ? wv.z : 0.0f);
    r.w = f2bf(mv.w >= 0.005f ? wv.w : 0.0f);
    ((ushort4*)o2)[i] = r;
  }
}

// ---------- 256x256 8-phase GEMM (qkv): C[M,N] = A[M,K]*B[N,K]^T + bias ----------
// T3+T4+T5 port of the proven 8-phase template. 8 waves (2M x 4N), per-wave
// output 128x64 (acc[8][4]). LDS 128 KB: [buf][half] for A and B, halves are
// 128 rows x 64 cols, XOR chunk-swizzled (chunk c at slot c^(row&7), global
// source pre-permuted, lds-dma dest linear). Per tile t (BK=64): 4 phases,
// each { ds_read af (4x b128; +8 bfr at p0) ; stage 1 half-tile (2 lds-dma);
// s_barrier ; setprio(1) 16 MFMA setprio(0) ; [p3: counted vmcnt] ; s_barrier }.
// Stage order: p0->A0(t+1) p1->A1(t+1) p2->B0(t+2) p3->B1(t+2).
// Steady-state vmcnt(4) at p3 leaves B(t+2)'s 4 loads in flight while
// guaranteeing ALL of tile t+1 has landed (its A staged p0/p1 this tile,
// its B staged p2/p3 last tile -> all older than the newest 4).
// Race audit: B-halves read only at p0 (overwrite from same-parity tile-2's
// p2 is 2+ barriers after the reads complete); A-halves of buf^1 are dead
// once the prior same-buffer tile's end barrier passed.
__global__ __launch_bounds__(512, 2) void k_gemm256(
    const unsigned short* __restrict__ A,
    const unsigned short* __restrict__ Bw,
    const float* __restrict__ bias,
    unsigned short* __restrict__ Cout,
    int Nn, int K)
{
  __shared__ unsigned short As[2][2][128 * 64];   // [buf][half] 16 KB each
  __shared__ unsigned short Bs[2][2][128 * 64];
  const int tid = threadIdx.x, lane = tid & 63;
  const int wid = tid >> 6;
  const int wr = wid >> 2, wc = wid & 3;          // 2M x 4N wave grid
  const int q4 = lane >> 4, r = lane & 15;
  const long bm = (long)blockIdx.x * 256, bn = (long)blockIdx.y * 256;

  f32x4 acc[8][4] = {};

  // staging offsets: slot s = l*512+tid ; row = s>>3 ; chunk = (s&7)^(row&7)
  int srow[2], sco[2];
#pragma unroll
  for (int l = 0; l < 2; ++l) {
    const int s = l * 512 + tid;
    srow[l] = s >> 3;
    sco[l] = ((s & 7) ^ (srow[l] & 7)) * 16;      // byte offset in 128-B row
  }

  auto stageA = [&](int t, int hf) {
    const int buf = t & 1, k0 = t * 64;
#pragma unroll
    for (int l = 0; l < 2; ++l)
      async_ld16((char*)As[buf][hf] + (l * 512 + tid) * 16,
                 (const char*)(A + (bm + hf * 128 + srow[l]) * (long)K + k0) + sco[l]);
  };
  auto stageB = [&](int t, int hf) {
    const int buf = t & 1, k0 = t * 64;
#pragma unroll
    for (int l = 0; l < 2; ++l)
      async_ld16((char*)Bs[buf][hf] + (l * 512 + tid) * 16,
                 (const char*)(Bw + (bn + hf * 128 + srow[l]) * (long)K + k0) + sco[l]);
  };

  const int NT = K >> 6;
  // prologue: T0 fully + T1's B-halves (12 loads); drain T0's 8.
  stageB(0, 0); stageB(0, 1); stageA(0, 0); stageA(0, 1);
  stageB(1, 0); stageB(1, 1);
  asm volatile("s_waitcnt vmcnt(4)" ::: "memory");
  __builtin_amdgcn_s_barrier();

  for (int t = 0; t < NT; ++t) {
    const int buf = t & 1;
    const unsigned short* Ah = As[buf][wr];        // this wave's A half
    const unsigned short* Bh = Bs[buf][wc >> 1];   // this wave's B half
    bf16x8 bfr[4][2];
#pragma unroll
    for (int p = 0; p < 4; ++p) {
      bf16x8 af[2][2];
#pragma unroll
      for (int ii = 0; ii < 2; ++ii) {
        const int lr = (p * 2 + ii) * 16 + r;      // row within half
#pragma unroll
        for (int kk = 0; kk < 2; ++kk) {
          const int ch = (kk * 4 + q4) ^ (lr & 7);
          af[ii][kk] = *(const bf16x8*)(Ah + lr * 64 + ch * 8);
        }
      }
      if (p == 0) {
#pragma unroll
        for (int j = 0; j < 4; ++j) {
          const int lr = (wc & 1) * 64 + j * 16 + r;
#pragma unroll
          for (int kk = 0; kk < 2; ++kk) {
            const int ch = (kk * 4 + q4) ^ (lr & 7);
            bfr[j][kk] = *(const bf16x8*)(Bh + lr * 64 + ch * 8);
          }
        }
      }
      // stage one half-tile
      if (p == 0)      { if (t + 1 < NT) stageA(t + 1, 0); }
      else if (p == 1) { if (t + 1 < NT) stageA(t + 1, 1); }
      else if (p == 2) { if (t + 2 < NT) stageB(t + 2, 0); }
      else             { if (t + 2 < NT) stageB(t + 2, 1); }

      __builtin_amdgcn_s_barrier();
      __builtin_amdgcn_s_setprio(1);
#pragma unroll
      for (int ii = 0; ii < 2; ++ii)
#pragma unroll
        for (int j = 0; j < 4; ++j)
#pragma unroll
          for (int kk = 0; kk < 2; ++kk)
            acc[p * 2 + ii][j] = __builtin_amdgcn_mfma_f32_16x16x32_bf16(
                af[ii][kk], bfr[j][kk], acc[p * 2 + ii][j], 0, 0, 0);
      __builtin_amdgcn_s_setprio(0);
      if (p == 3) {
        if (t + 2 < NT) asm volatile("s_waitcnt vmcnt(4)" ::: "memory");
        else            asm volatile("s_waitcnt vmcnt(0)" ::: "memory");
      }
      __builtin_amdgcn_s_barrier();
    }
  }

  // epilogue: bf16 out + bias
#pragma unroll
  for (int j = 0; j < 4; ++j) {
    const long col = bn + wc * 64 + j * 16 + r;
    const float bv = bias[col];
#pragma unroll
    for (int i2 = 0; i2 < 8; ++i2) {
#pragma unroll
      for (int rr = 0; rr < 4; ++rr) {
        const long rowg = bm + wr * 128 + i2 * 16 + q4 * 4 + rr;
        Cout[rowg * Nn + col] = f2bf(acc[i2][j][rr] + bv);
      }
    }
  }
}

// ---------- GEMM 128x128 (proj): unchanged counted-vmcnt dbuf ----------
template <bool OUT_BF16>
__global__ __launch_bounds__(256) void k_gemm_bt(
    const unsigned short* __restrict__ A,
    const unsigned short* __restrict__ Bw,
    const float* __restrict__ bias,
    void* __restrict__ Cout,
    int M, int Nn, int K)
{
  __shared__ unsigned short As[2][128 * 64];   // 16 KB per buf
  __shared__ unsigned short Bs[2][128 * 64];
  const int tid = threadIdx.x, lane = tid & 63;
  const int wv = tid >> 6, wr = wv >> 1, wc = wv & 1;
  const int q4 = lane >> 4, r = lane & 15;
  const long bm = (long)blockIdx.x * 128, bn = (long)blockIdx.y * 128;

  f32x4 acc[4][4] = {};

  int srow[4], sco[4];
#pragma unroll
  for (int j = 0; j < 4; ++j) {
    const int s = j * 256 + tid;
    srow[j] = s >> 3;
    sco[j] = ((s & 7) ^ (srow[j] & 7)) * 16;
  }

  auto stage = [&](int k0, int buf) {
#pragma unroll
    for (int j = 0; j < 4; ++j) {
      const int ldsoff = j * 4096 + tid * 16;
      async_ld16((char*)As[buf] + ldsoff,
                 (const char*)(A + (bm + srow[j]) * (long)K + k0) + sco[j]);
      async_ld16((char*)Bs[buf] + ldsoff,
                 (const char*)(Bw + (bn + srow[j]) * (long)K + k0) + sco[j]);
    }
  };

  stage(0, 0);

  const int NT = K >> 6;
  for (int t = 0; t < NT; ++t) {
    const int cur = t & 1;
    if (t + 1 < NT) {
      stage((t + 1) * 64, cur ^ 1);
      asm volatile("s_waitcnt vmcnt(8)" ::: "memory");
    } else {
      asm volatile("s_waitcnt vmcnt(0)" ::: "memory");
    }
    __builtin_amdgcn_s_barrier();
    __builtin_amdgcn_sched_barrier(0);

    const unsigned short* Ac = As[cur];
    const unsigned short* Bc = Bs[cur];

#pragma unroll
    for (int ks = 0; ks < 2; ++ks) {
      bf16x8 af[4], bfr[4];
#pragma unroll
      for (int i = 0; i < 4; ++i) {
        const int row = wr * 64 + i * 16 + r;
        const int ch = (ks * 4 + q4) ^ (row & 7);
        af[i] = *(const bf16x8*)(Ac + row * 64 + ch * 8);
      }
#pragma unroll
      for (int j = 0; j < 4; ++j) {
        const int row = wc * 64 + j * 16 + r;
        const int ch = (ks * 4 + q4) ^ (row & 7);
        bfr[j] = *(const bf16x8*)(Bc + row * 64 + ch * 8);
      }
#pragma unroll
      for (int i = 0; i < 4; ++i)
#pragma unroll
        for (int j = 0; j < 4; ++j)
          acc[i][j] = __builtin_amdgcn_mfma_f32_16x16x32_bf16(af[i], bfr[j], acc[i][j], 0, 0, 0);
    }
    __builtin_amdgcn_sched_barrier(0);
    __builtin_amdgcn_s_barrier();
  }

#pragma unroll
  for (int j = 0; j < 4; ++j) {
    const long col = bn + wc * 64 + j * 16 + r;
    const float bv = bias[col];
#pragma unroll
    for (int i = 0; i < 4; ++i) {
#pragma unroll
      for (int rr = 0; rr < 4; ++rr) {
        const long rowg = bm + wr * 64 + i * 16 + q4 * 4 + rr;
        const float v = acc[i][j][rr] + bv;
        if (OUT_BF16)
          ((unsigned short*)Cout)[rowg * Nn + col] = f2bf(v);
        else
          ((float*)Cout)[rowg * Nn + col] = v;
      }
    }
  }
}

// ---------- transpose V: qkv[b,n,2C + h*64 + d] -> vt[(bh*64+d)*1024 + n] ----------
__global__ __launch_bounds__(256) void k_transpose_v(const unsigned short* __restrict__ qkv,
                                                     unsigned short* __restrict__ vt) {
  __shared__ unsigned short T[64][72];
  const int tid = threadIdx.x;
  const int bh = blockIdx.y, b = bh / 12, h = bh % 12;
  const int n0 = blockIdx.x * 64;
#pragma unroll
  for (int i = 0; i < 2; ++i) {
    int c = tid + i * 256, row = c >> 3, ch = c & 7;
    uint4 v = *(const uint4*)(qkv + ((long)(b * 1024 + n0 + row)) * 2304 + 1536 + h * 64 + ch * 8);
    *(uint4*)(&T[row][ch * 8]) = v;
  }
  __syncthreads();
#pragma unroll
  for (int i = 0; i < 2; ++i) {
    int c = tid + i * 256, d = c >> 3, ch = c & 7;
    unsigned short tmp[8];
#pragma unroll
    for (int j = 0; j < 8; ++j) tmp[j] = T[ch * 8 + j][d];
    *(uint4*)(vt + ((long)bh * 64 + d) * 1024 + n0 + ch * 8) = *(const uint4*)tmp;
  }
}

// ---------- flash attention (unchanged: XCD remap + exp2 fold dbuf) ----------
__global__ __launch_bounds__(256) void k_flash(
    const unsigned short* __restrict__ qkv,  // [8192, 2304]
    const unsigned short* __restrict__ vt,   // [96*64, 1024]
    unsigned short* __restrict__ outp)       // [8192, 768]
{
  constexpr int LDP = 72;
  __shared__ unsigned short Ks[2][64 * 64];
  __shared__ unsigned short Vts[2][64 * 64];
  __shared__ unsigned short Ps[4 * 32 * LDP];

  const int tid = threadIdx.x, lane = tid & 63;
  const int wv = tid >> 6, q4 = lane >> 4, r = lane & 15;

  const int nlin = blockIdx.y * 8 + blockIdx.x;
  const int bh = (nlin & 7) * 12 + (nlin >> 6);
  const int q0 = ((nlin >> 3) & 7) * 128;
  const int b = bh / 12, h = bh % 12;
  const long qrow0 = (long)b * 1024;

  int srow[2], sco[2];
#pragma unroll
  for (int i = 0; i < 2; ++i) {
    const int s = i * 256 + tid;
    srow[i] = s >> 3;
    sco[i] = ((s & 7) ^ (srow[i] & 7)) * 8;
  }

  const unsigned short* Kg = qkv + qrow0 * 2304 + 768 + (long)h * 64;
  const unsigned short* Vg = vt + (long)bh * 64 * 1024;

  bf16x8 aq[2][2];
#pragma unroll
  for (int i = 0; i < 2; ++i)
#pragma unroll
    for (int kc = 0; kc < 2; ++kc)
      aq[i][kc] = *(const bf16x8*)(qkv + (qrow0 + q0 + wv * 32 + i * 16 + r) * 2304 + h * 64 + kc * 32 + q4 * 8);

  f32x4 o[2][4] = {};
  f32x4 lsum[2] = {};
  const bf16x8 ones = {0x3F80, 0x3F80, 0x3F80, 0x3F80, 0x3F80, 0x3F80, 0x3F80, 0x3F80};

  auto stage = [&](int n0, int buf) {
#pragma unroll
    for (int i = 0; i < 2; ++i) {
      const int ldsoff = (i * 256 + tid) * 16;
      async_ld16((char*)Ks[buf] + ldsoff,
                 (const void*)(Kg + (long)(n0 + srow[i]) * 2304 + sco[i]));
      async_ld16((char*)Vts[buf] + ldsoff,
                 (const void*)(Vg + (long)srow[i] * 1024 + n0 + sco[i]));
    }
  };

  stage(0, 0);

  for (int kt = 0; kt < 16; ++kt) {
    const int cur = kt & 1;
    __syncthreads();
    if (kt < 15) stage((kt + 1) * 64, cur ^ 1);

    const unsigned short* Kc = Ks[cur];
    const unsigned short* Vc = Vts[cur];

    f32x4 s[2][4] = {};
    {
      bf16x8 bk[4][2];
#pragma unroll
      for (int j = 0; j < 4; ++j)
#pragma unroll
        for (int kc = 0; kc < 2; ++kc) {
          const int row = j * 16 + r;
          const int ch = (kc * 4 + q4) ^ (row & 7);
          bk[j][kc] = *(const bf16x8*)(Kc + row * 64 + ch * 8);
        }
#pragma unroll
      for (int i = 0; i < 2; ++i)
#pragma unroll
        for (int j = 0; j < 4; ++j) {
          s[i][j] = __builtin_amdgcn_mfma_f32_16x16x32_bf16(aq[i][0], bk[j][0], s[i][j], 0, 0, 0);
          s[i][j] = __builtin_amdgcn_mfma_f32_16x16x32_bf16(aq[i][1], bk[j][1], s[i][j], 0, 0, 0);
        }
    }

#pragma unroll
    for (int i = 0; i < 2; ++i)
#pragma unroll
      for (int j = 0; j < 4; ++j)
#pragma unroll
        for (int rr = 0; rr < 4; ++rr) {
          float p = __builtin_amdgcn_exp2f(fmaf(s[i][j][rr], 0.18033688f, -2.88539008f));
          Ps[(wv * 32 + i * 16 + q4 * 4 + rr) * LDP + j * 16 + r] = f2bf(p);
        }

    {
      bf16x8 bv[4][2];
#pragma unroll
      for (int jd = 0; jd < 4; ++jd)
#pragma unroll
        for (int kc = 0; kc < 2; ++kc) {
          const int row = jd * 16 + r;
          const int ch = (kc * 4 + q4) ^ (row & 7);
          bv[jd][kc] = *(const bf16x8*)(Vc + row * 64 + ch * 8);
        }
#pragma unroll
      for (int i = 0; i < 2; ++i) {
        bf16x8 ap0 = *(const bf16x8*)(Ps + (wv * 32 + i * 16 + r) * LDP + 0 + q4 * 8);
        bf16x8 ap1 = *(const bf16x8*)(Ps + (wv * 32 + i * 16 + r) * LDP + 32 + q4 * 8);
        lsum[i] = __builtin_amdgcn_mfma_f32_16x16x32_bf16(ap0, ones, lsum[i], 0, 0, 0);
        lsum[i] = __builtin_amdgcn_mfma_f32_16x16x32_bf16(ap1, ones, lsum[i], 0, 0, 0);
#pragma unroll
        for (int jd = 0; jd < 4; ++jd) {
          o[i][jd] = __builtin_amdgcn_mfma_f32_16x16x32_bf16(ap0, bv[jd][0], o[i][jd], 0, 0, 0);
          o[i][jd] = __builtin_amdgcn_mfma_f32_16x16x32_bf16(ap1, bv[jd][1], o[i][jd], 0, 0, 0);
        }
      }
    }
  }

#pragma unroll
  for (int i = 0; i < 2; ++i)
#pragma unroll
    for (int rr = 0; rr < 4; ++rr) {
      const float inv = 1.0f / lsum[i][rr];
      const long rowg = qrow0 + q0 + wv * 32 + i * 16 + q4 * 4 + rr;
#pragma unroll
      for (int jd = 0; jd < 4; ++jd)
        outp[rowg * 768 + h * 64 + jd * 16 + r] = f2bf(o[i][jd][rr] * inv);
    }
}

// ---------- launcher ----------
extern "C" void kernel_launch(void* const* d_in, const int* in_sizes, int n_in,
                              void* d_out, int out_size, void* d_ws, size_t ws_size,
                              hipStream_t stream) {
  const float* x      = (const float*)d_in[0];
  const float* qkv_w  = (const float*)d_in[1];
  const float* qkv_b  = (const float*)d_in[2];
  const float* proj_w = (const float*)d_in[3];
  const float* proj_b = (const float*)d_in[4];
  const float* mask   = (const float*)d_in[5];
  const float* mask_p = (const float*)d_in[6];

  char* ws = (char*)d_ws;
  unsigned short* qkv   = (unsigned short*)(ws);              // 8192*2304*2
  unsigned short* vt    = (unsigned short*)(ws + 37748736);   // 96*64*1024*2
  unsigned short* xbf   = (unsigned short*)(ws + 50331648);   // 8192*768*2 (reused as attn out)
  unsigned short* wqkv  = (unsigned short*)(ws + 62914560);   // 2304*768*2
  unsigned short* wproj = (unsigned short*)(ws + 66453504);   // 768*768*2

  k_prep<<<8448, 256, 0, stream>>>(x, xbf, qkv_w, mask, wqkv, proj_w, mask_p, wproj);
  k_gemm256<<<dim3(32, 9), 512, 0, stream>>>(xbf, wqkv, qkv_b, qkv, 2304, 768);
  k_transpose_v<<<dim3(16, 96), 256, 0, stream>>>(qkv, vt);
  k_flash<<<dim3(8, 96), 256, 0, stream>>>(qkv, vt, xbf);
  k_gemm_bt<false><<<dim3(64, 6), 256, 0, stream>>>(xbf, wproj, proj_b, d_out, 8192, 768, 768);
}

// Round 7
// 191.613 us; speedup vs baseline: 1.1360x; 1.1360x over previous
//
#include <hip/hip_runtime.h>
#include <hip/hip_bf16.h>

// ---------- types ----------
typedef short bf16x8 __attribute__((ext_vector_type(8)));
typedef float f32x4 __attribute__((ext_vector_type(4)));

typedef __attribute__((address_space(3))) unsigned int lds_u32;
typedef __attribute__((address_space(1))) const unsigned int gbl_cu32;

__device__ __forceinline__ void async_ld16(void* lds, const void* g) {
  __builtin_amdgcn_global_load_lds((gbl_cu32*)g, (lds_u32*)lds, 16, 0, 0);
}

__device__ __forceinline__ unsigned short f2bf(float f) {
  unsigned u = __builtin_bit_cast(unsigned, f);
  u += 0x7FFFu + ((u >> 16) & 1u);   // RNE; inputs finite
  return (unsigned short)(u >> 16);
}

// ---------- prep (merged): x->bf16, mask(qkv_w), mask(proj_w) ----------
__global__ void k_prep(const float* __restrict__ x, unsigned short* __restrict__ xo,
                       const float* __restrict__ w1, const float* __restrict__ m1,
                       unsigned short* __restrict__ o1,
                       const float* __restrict__ w2, const float* __restrict__ m2,
                       unsigned short* __restrict__ o2) {
  int blk = blockIdx.x;
  if (blk < 6144) {
    int i = blk * 256 + threadIdx.x;
    float4 v = ((const float4*)x)[i];
    ushort4 r;
    r.x = f2bf(v.x); r.y = f2bf(v.y); r.z = f2bf(v.z); r.w = f2bf(v.w);
    ((ushort4*)xo)[i] = r;
  } else if (blk < 6144 + 1728) {
    int i = (blk - 6144) * 256 + threadIdx.x;
    float4 wv = ((const float4*)w1)[i];
    float4 mv = ((const float4*)m1)[i];
    ushort4 r;
    r.x = f2bf(mv.x >= 0.005f ? wv.x : 0.0f);
    r.y = f2bf(mv.y >= 0.005f ? wv.y : 0.0f);
    r.z = f2bf(mv.z >= 0.005f ? wv.z : 0.0f);
    r.w = f2bf(mv.w >= 0.005f ? wv.w : 0.0f);
    ((ushort4*)o1)[i] = r;
  } else {
    int i = (blk - 6144 - 1728) * 256 + threadIdx.x;
    float4 wv = ((const float4*)w2)[i];
    float4 mv = ((const float4*)m2)[i];
    ushort4 r;
    r.x = f2bf(mv.x >= 0.005f ? wv.x : 0.0f);
    r.y = f2bf(mv.y >= 0.005f ? wv.y : 0.0f);
    r.z = f2bf(mv.z >= 0.005f ? wv.z : 0.0f);
    r.w = f2bf(mv.w >= 0.005f ? wv.w : 0.0f);
    ((ushort4*)o2)[i] = r;
  }
}

// ---------- GEMM: C[M,N] = A[M,K] * B[N,K]^T + bias[N] ----------
// REVERTED to the proven round-5 2-phase counted-vmcnt dbuf (the 8-phase
// 256^2 port regressed 49.7->73us: phase-split without the exact fine
// interleave + 1 block/CU = m196/m232's documented failure mode).
// NEW this round (VT path): qkv blocks with bn>=1536 compute the V third;
// instead of writing it to the qkv buffer (only the transpose kernel read
// it), they transpose their 128x128 tile through the (dead) staging LDS
// and write vt directly -> k_transpose_v kernel deleted, 25 MB HBM
// round-trip eliminated.
template <bool OUT_BF16, bool VT>
__global__ __launch_bounds__(256) void k_gemm_bt(
    const unsigned short* __restrict__ A,
    const unsigned short* __restrict__ Bw,
    const float* __restrict__ bias,
    void* __restrict__ Cout,
    unsigned short* __restrict__ vtp,
    int M, int Nn, int K)
{
  // unified LDS: staging = [A:2x16KB][B:2x16KB]; epilogue reuses it as
  // transpose scratch T[128 cols][136] (34.8 KB <= 64 KB).
  __shared__ unsigned short SH[32768];
  const int tid = threadIdx.x, lane = tid & 63;
  const int wv = tid >> 6, wr = wv >> 1, wc = wv & 1;
  const int q4 = lane >> 4, r = lane & 15;
  const long bm = (long)blockIdx.x * 128, bn = (long)blockIdx.y * 128;

  f32x4 acc[4][4] = {};

  // slot s = j*256+tid ; row = s>>3 ; chunk c' = s&7 ; global chunk = c'^(row&7)
  int srow[4], sco[4];
#pragma unroll
  for (int j = 0; j < 4; ++j) {
    const int s = j * 256 + tid;
    srow[j] = s >> 3;
    sco[j] = ((s & 7) ^ (srow[j] & 7)) * 16;  // byte offset within 128-B row
  }

  auto stage = [&](int k0, int buf) {
    char* Abase = (char*)SH + buf * 16384;
    char* Bbase = (char*)SH + 32768 + buf * 16384;
#pragma unroll
    for (int j = 0; j < 4; ++j) {
      const int ldsoff = j * 4096 + tid * 16;
      async_ld16(Abase + ldsoff,
                 (const char*)(A + (bm + srow[j]) * (long)K + k0) + sco[j]);
      async_ld16(Bbase + ldsoff,
                 (const char*)(Bw + (bn + srow[j]) * (long)K + k0) + sco[j]);
    }
  };

  stage(0, 0);  // prologue prefetch

  const int NT = K >> 6;
  for (int t = 0; t < NT; ++t) {
    const int cur = t & 1;
    if (t + 1 < NT) {
      stage((t + 1) * 64, cur ^ 1);                       // 16 loads outstanding
      asm volatile("s_waitcnt vmcnt(8)" ::: "memory");    // stage(t) landed
    } else {
      asm volatile("s_waitcnt vmcnt(0)" ::: "memory");
    }
    __builtin_amdgcn_s_barrier();        // all waves' stage(t) visible
    __builtin_amdgcn_sched_barrier(0);   // pin ds_reads below (rule 18)

    const unsigned short* Ac = SH + cur * 8192;
    const unsigned short* Bc = SH + 16384 + cur * 8192;

#pragma unroll
    for (int ks = 0; ks < 2; ++ks) {
      bf16x8 af[4], bfr[4];
#pragma unroll
      for (int i = 0; i < 4; ++i) {
        const int row = wr * 64 + i * 16 + r;
        const int ch = (ks * 4 + q4) ^ (row & 7);
        af[i] = *(const bf16x8*)(Ac + row * 64 + ch * 8);
      }
#pragma unroll
      for (int j = 0; j < 4; ++j) {
        const int row = wc * 64 + j * 16 + r;
        const int ch = (ks * 4 + q4) ^ (row & 7);
        bfr[j] = *(const bf16x8*)(Bc + row * 64 + ch * 8);
      }
#pragma unroll
      for (int i = 0; i < 4; ++i)
#pragma unroll
        for (int j = 0; j < 4; ++j)
          acc[i][j] = __builtin_amdgcn_mfma_f32_16x16x32_bf16(af[i], bfr[j], acc[i][j], 0, 0, 0);
    }
    __builtin_amdgcn_sched_barrier(0);
    __builtin_amdgcn_s_barrier();        // all waves done reading buf[cur]
  }

  if (VT && blockIdx.y >= 12) {
    // ---- V path: transpose tile through LDS, write vt[(b*768+hv)*1024+n]
    __syncthreads();   // staging LDS dead; make all waves' reads ordered
    unsigned short* T = SH;                       // T[c][136], c = 0..127
#pragma unroll
    for (int j = 0; j < 4; ++j) {
      const int c = wc * 64 + j * 16 + r;         // output col within tile
      const float bv = bias[bn + c];
#pragma unroll
      for (int i = 0; i < 4; ++i) {
        const int row0 = wr * 64 + i * 16 + q4 * 4;
        ushort4 t4;
        t4.x = f2bf(acc[i][j][0] + bv);
        t4.y = f2bf(acc[i][j][1] + bv);
        t4.z = f2bf(acc[i][j][2] + bv);
        t4.w = f2bf(acc[i][j][3] + bv);
        *(ushort4*)(T + c * 136 + row0) = t4;     // 8B aligned (136c+row0)
      }
    }
    __syncthreads();
    const int bq = (int)(bm >> 10);               // batch
    const int n_base = (int)(bm & 1023);          // n offset of tile rows
    const long vrow0 = (long)bq * 768 + (bn - 1536);
#pragma unroll
    for (int it = 0; it < 8; ++it) {
      const int idx = it * 256 + tid;
      const int c = idx >> 4, seg = idx & 15;
      uint4 v = *(const uint4*)(T + c * 136 + seg * 8);
      *(uint4*)(vtp + (vrow0 + c) * 1024 + n_base + seg * 8) = v;
    }
  } else {
    // ---- normal C write (+bias) ----
#pragma unroll
    for (int j = 0; j < 4; ++j) {
      const long col = bn + wc * 64 + j * 16 + r;
      const float bv = bias[col];
#pragma unroll
      for (int i = 0; i < 4; ++i) {
#pragma unroll
        for (int rr = 0; rr < 4; ++rr) {
          const long rowg = bm + wr * 64 + i * 16 + q4 * 4 + rr;
          const float v = acc[i][j][rr] + bv;
          if (OUT_BF16)
            ((unsigned short*)Cout)[rowg * Nn + col] = f2bf(v);
          else
            ((float*)Cout)[rowg * Nn + col] = v;
        }
      }
    }
  }
}

// ---------- flash attention (unchanged: XCD remap + exp2 fold dbuf) ----------
__global__ __launch_bounds__(256) void k_flash(
    const unsigned short* __restrict__ qkv,  // [8192, 2304] (V third unused)
    const unsigned short* __restrict__ vt,   // [96*64, 1024]
    unsigned short* __restrict__ outp)       // [8192, 768]
{
  constexpr int LDP = 72;
  __shared__ unsigned short Ks[2][64 * 64];
  __shared__ unsigned short Vts[2][64 * 64];
  __shared__ unsigned short Ps[4 * 32 * LDP];

  const int tid = threadIdx.x, lane = tid & 63;
  const int wv = tid >> 6, q4 = lane >> 4, r = lane & 15;

  const int nlin = blockIdx.y * 8 + blockIdx.x;
  const int bh = (nlin & 7) * 12 + (nlin >> 6);
  const int q0 = ((nlin >> 3) & 7) * 128;
  const int b = bh / 12, h = bh % 12;
  const long qrow0 = (long)b * 1024;

  int srow[2], sco[2];
#pragma unroll
  for (int i = 0; i < 2; ++i) {
    const int s = i * 256 + tid;
    srow[i] = s >> 3;
    sco[i] = ((s & 7) ^ (srow[i] & 7)) * 8;
  }

  const unsigned short* Kg = qkv + qrow0 * 2304 + 768 + (long)h * 64;
  const unsigned short* Vg = vt + (long)bh * 64 * 1024;

  bf16x8 aq[2][2];
#pragma unroll
  for (int i = 0; i < 2; ++i)
#pragma unroll
    for (int kc = 0; kc < 2; ++kc)
      aq[i][kc] = *(const bf16x8*)(qkv + (qrow0 + q0 + wv * 32 + i * 16 + r) * 2304 + h * 64 + kc * 32 + q4 * 8);

  f32x4 o[2][4] = {};
  f32x4 lsum[2] = {};
  const bf16x8 ones = {0x3F80, 0x3F80, 0x3F80, 0x3F80, 0x3F80, 0x3F80, 0x3F80, 0x3F80};

  auto stage = [&](int n0, int buf) {
#pragma unroll
    for (int i = 0; i < 2; ++i) {
      const int ldsoff = (i * 256 + tid) * 16;
      async_ld16((char*)Ks[buf] + ldsoff,
                 (const void*)(Kg + (long)(n0 + srow[i]) * 2304 + sco[i]));
      async_ld16((char*)Vts[buf] + ldsoff,
                 (const void*)(Vg + (long)srow[i] * 1024 + n0 + sco[i]));
    }
  };

  stage(0, 0);

  for (int kt = 0; kt < 16; ++kt) {
    const int cur = kt & 1;
    __syncthreads();
    if (kt < 15) stage((kt + 1) * 64, cur ^ 1);

    const unsigned short* Kc = Ks[cur];
    const unsigned short* Vc = Vts[cur];

    f32x4 s[2][4] = {};
    {
      bf16x8 bk[4][2];
#pragma unroll
      for (int j = 0; j < 4; ++j)
#pragma unroll
        for (int kc = 0; kc < 2; ++kc) {
          const int row = j * 16 + r;
          const int ch = (kc * 4 + q4) ^ (row & 7);
          bk[j][kc] = *(const bf16x8*)(Kc + row * 64 + ch * 8);
        }
#pragma unroll
      for (int i = 0; i < 2; ++i)
#pragma unroll
        for (int j = 0; j < 4; ++j) {
          s[i][j] = __builtin_amdgcn_mfma_f32_16x16x32_bf16(aq[i][0], bk[j][0], s[i][j], 0, 0, 0);
          s[i][j] = __builtin_amdgcn_mfma_f32_16x16x32_bf16(aq[i][1], bk[j][1], s[i][j], 0, 0, 0);
        }
    }

#pragma unroll
    for (int i = 0; i < 2; ++i)
#pragma unroll
      for (int j = 0; j < 4; ++j)
#pragma unroll
        for (int rr = 0; rr < 4; ++rr) {
          float p = __builtin_amdgcn_exp2f(fmaf(s[i][j][rr], 0.18033688f, -2.88539008f));
          Ps[(wv * 32 + i * 16 + q4 * 4 + rr) * LDP + j * 16 + r] = f2bf(p);
        }

    {
      bf16x8 bv[4][2];
#pragma unroll
      for (int jd = 0; jd < 4; ++jd)
#pragma unroll
        for (int kc = 0; kc < 2; ++kc) {
          const int row = jd * 16 + r;
          const int ch = (kc * 4 + q4) ^ (row & 7);
          bv[jd][kc] = *(const bf16x8*)(Vc + row * 64 + ch * 8);
        }
#pragma unroll
      for (int i = 0; i < 2; ++i) {
        bf16x8 ap0 = *(const bf16x8*)(Ps + (wv * 32 + i * 16 + r) * LDP + 0 + q4 * 8);
        bf16x8 ap1 = *(const bf16x8*)(Ps + (wv * 32 + i * 16 + r) * LDP + 32 + q4 * 8);
        lsum[i] = __builtin_amdgcn_mfma_f32_16x16x32_bf16(ap0, ones, lsum[i], 0, 0, 0);
        lsum[i] = __builtin_amdgcn_mfma_f32_16x16x32_bf16(ap1, ones, lsum[i], 0, 0, 0);
#pragma unroll
        for (int jd = 0; jd < 4; ++jd) {
          o[i][jd] = __builtin_amdgcn_mfma_f32_16x16x32_bf16(ap0, bv[jd][0], o[i][jd], 0, 0, 0);
          o[i][jd] = __builtin_amdgcn_mfma_f32_16x16x32_bf16(ap1, bv[jd][1], o[i][jd], 0, 0, 0);
        }
      }
    }
  }

#pragma unroll
  for (int i = 0; i < 2; ++i)
#pragma unroll
    for (int rr = 0; rr < 4; ++rr) {
      const float inv = 1.0f / lsum[i][rr];
      const long rowg = qrow0 + q0 + wv * 32 + i * 16 + q4 * 4 + rr;
#pragma unroll
      for (int jd = 0; jd < 4; ++jd)
        outp[rowg * 768 + h * 64 + jd * 16 + r] = f2bf(o[i][jd][rr] * inv);
    }
}

// ---------- launcher ----------
extern "C" void kernel_launch(void* const* d_in, const int* in_sizes, int n_in,
                              void* d_out, int out_size, void* d_ws, size_t ws_size,
                              hipStream_t stream) {
  const float* x      = (const float*)d_in[0];
  const float* qkv_w  = (const float*)d_in[1];
  const float* qkv_b  = (const float*)d_in[2];
  const float* proj_w = (const float*)d_in[3];
  const float* proj_b = (const float*)d_in[4];
  const float* mask   = (const float*)d_in[5];
  const float* mask_p = (const float*)d_in[6];

  char* ws = (char*)d_ws;
  unsigned short* qkv   = (unsigned short*)(ws);              // 8192*2304*2 (V third unused)
  unsigned short* vt    = (unsigned short*)(ws + 37748736);   // 96*64*1024*2
  unsigned short* xbf   = (unsigned short*)(ws + 50331648);   // 8192*768*2 (reused as attn out)
  unsigned short* wqkv  = (unsigned short*)(ws + 62914560);   // 2304*768*2
  unsigned short* wproj = (unsigned short*)(ws + 66453504);   // 768*768*2

  k_prep<<<8448, 256, 0, stream>>>(x, xbf, qkv_w, mask, wqkv, proj_w, mask_p, wproj);
  k_gemm_bt<true, true><<<dim3(64, 18), 256, 0, stream>>>(xbf, wqkv, qkv_b, qkv, vt, 8192, 2304, 768);
  k_flash<<<dim3(8, 96), 256, 0, stream>>>(qkv, vt, xbf);
  k_gemm_bt<false, false><<<dim3(64, 6), 256, 0, stream>>>(xbf, wproj, proj_b, d_out, nullptr, 8192, 768, 768);
}